// Round 10
// baseline (349.125 us; speedup 1.0000x reference)
//
#include <hip/hip_runtime.h>
#include <stdint.h>

#define O_FEATS 28672
#define I_FEATS 8192
#define BATCH 8
#define PITCH_WB 8208                 // bytes per LDS W row (8192 + 16 pad; 2052 words ≡ 4 mod 32 -> conflict-free frag reads)
#define HALF_B (8 * PITCH_WB)         // one half-tile buffer: 65,664 B

typedef int i32x4 __attribute__((ext_vector_type(4)));

// Barriers: inline asm with "memory" clobber so no IR/MIR pass can move
// LDS/global ops across them. vmcnt(16) keeps the freshly-issued next-phase
// DMAs (16/wave) in flight across the barrier; vmcnt(0) full drain (last
// phase); lgkmcnt(0) ensures this wave's ds_reads completed before other
// waves may overwrite the buffer.
#define BAR_VM16 asm volatile("s_waitcnt vmcnt(16)\n\ts_barrier" ::: "memory")
#define BAR_VM0  asm volatile("s_waitcnt vmcnt(0)\n\ts_barrier" ::: "memory")
#define BAR_LGKM asm volatile("s_waitcnt lgkmcnt(0)\n\ts_barrier" ::: "memory")
#define BAR_ONLY asm volatile("s_barrier" ::: "memory")

// ---------------------------------------------------------------------------
// Workspace layout (uint32 word indices into ws):
//   ws[0]        : final absmax (float bits, >= 1e-5), written by k_quant
//   ws[16..79]   : per-block absmax partials (64 blocks of k_absmax)
//   ws[128..191] : per-block sum_x partials, index = b*8 + seg
//   ws[1024..]   : x_q TRANSPOSED to MFMA-fragment order, 128 KB:
//                  T[S*1024 + L*16 + j] = x_q[row L&15][k=S*64+(L>>4)*16+j]
//                  (S = global K-step 0..127, L = lane 0..63; rows 8..15 = 0)
// ---------------------------------------------------------------------------

// Carry-free unpack of 4 ternary codes (bits [7:0] of p) to 4 unsigned bytes
// {c0,c1,c2,c3} at byte positions 0..3 == k-offsets 0..3 of that word.
static __device__ __forceinline__ int unpack4(uint32_t p) {
  uint32_t lo = p & 0x0Fu;
  uint32_t hi = (p >> 4) & 0x0Fu;
  uint32_t a = (lo * 0x41u) & 0x0303u;
  uint32_t b = (hi * 0x41u) & 0x0303u;
  return (int)(a | (b << 16));
}

// 64 blocks x 256 threads x 4 floats = 65536 elements; per-block partial max.
__global__ void k_absmax(const float* __restrict__ x, uint32_t* __restrict__ ws) {
  __shared__ float red[4];
  int t = threadIdx.x;
  float4 v = ((const float4*)x)[blockIdx.x * 256 + t];
  float m = fmaxf(fmaxf(fabsf(v.x), fabsf(v.y)), fmaxf(fabsf(v.z), fabsf(v.w)));
#pragma unroll
  for (int off = 32; off; off >>= 1)
    m = fmaxf(m, __shfl_xor(m, off));
  if ((t & 63) == 0) red[t >> 6] = m;
  __syncthreads();
  if (t == 0)
    ws[16 + blockIdx.x] =
        __float_as_uint(fmaxf(fmaxf(red[0], red[1]), fmaxf(red[2], red[3])));
}

// 128 blocks. Blocks 0..63: (b = blk>>3, seg = blk&7) quantize 1024 elems of
// row b, write into transposed layout T + partial sums. Blocks 64..127:
// zero-fill pad rows 8..15 of T.
__global__ void k_quant(const float* __restrict__ x, uint32_t* __restrict__ ws) {
  __shared__ float s_amax;
  __shared__ int reds[4];
  int t = threadIdx.x;
  if (blockIdx.x >= 64) {  // zero pad rows 8..15 in T
    int row = 8 + ((blockIdx.x - 64) >> 3), seg = blockIdx.x & 7;
    int k0 = seg * 1024 + t * 4;
    int S = k0 >> 6, g = (k0 >> 4) & 3, j = k0 & 15;
    ws[1024 + ((S * 1024 + (g * 16 + row) * 16 + j) >> 2)] = 0u;
    return;
  }
  int b = blockIdx.x >> 3, seg = blockIdx.x & 7;
  if (t < 64) {  // reduce the 64 absmax partials (redundantly per block)
    float m = __uint_as_float(ws[16 + t]);
#pragma unroll
    for (int off = 32; off; off >>= 1)
      m = fmaxf(m, __shfl_xor(m, off));
    if (t == 0) {
      float a = fmaxf(m, 1e-5f);
      s_amax = a;
      ws[0] = __float_as_uint(a);  // same value from every block: benign
    }
  }
  __syncthreads();
  float s = s_amax / 127.0f;  // match ref: x / (absmax/127)
  float4 v = ((const float4*)(x + b * I_FEATS + seg * 1024))[t];
  int q0 = (int)fminf(fmaxf(rintf(v.x / s), -128.f), 127.f);
  int q1 = (int)fminf(fmaxf(rintf(v.y / s), -128.f), 127.f);
  int q2 = (int)fminf(fmaxf(rintf(v.z / s), -128.f), 127.f);
  int q3 = (int)fminf(fmaxf(rintf(v.w / s), -128.f), 127.f);
  uint32_t pk = (uint32_t)(q0 & 0xff) | ((uint32_t)(q1 & 0xff) << 8) |
                ((uint32_t)(q2 & 0xff) << 16) | ((uint32_t)(q3 & 0xff) << 24);
  {  // scatter into transposed fragment layout (4 B words, aligned)
    int k0 = seg * 1024 + t * 4;
    int S = k0 >> 6, g = (k0 >> 4) & 3, j = k0 & 15;
    ws[1024 + ((S * 1024 + (g * 16 + b) * 16 + j) >> 2)] = pk;
  }
  int s4 = q0 + q1 + q2 + q3;
#pragma unroll
  for (int off = 32; off; off >>= 1)
    s4 += __shfl_xor(s4, off);
  if ((t & 63) == 0) reds[t >> 6] = s4;
  __syncthreads();
  if (t == 0)
    ws[128 + blockIdx.x] = (uint32_t)(reds[0] + reds[1] + reds[2] + reds[3]);
}

// Persistent MFMA GEMM, contiguous-stream staging: 256 blocks (1/CU, forced
// by ~133 KB LDS), 7 tiles/block (tile = blk + 256*i). Per tile: 2 phases
// (half h = rows h*8..h*8+7, FULL 8 KB of K each, contiguous 64 KB/CU),
// double-buffered. Staging: wave w DMAs rows 2w,2w+1 (16 KB sequential) via
// 16x global_load_lds(16B). Canonical 2-barrier pipeline, asm-clobbered:
//   stage(next)->other buf; [vmcnt(16); barrier]; compute(this buf);
//   [lgkmcnt(0); barrier]   <- protects buf from next restage (R9's bug).
// Compute: wave w owns k-quarter [w*2048,(w+1)*2048); A-quarter in 128 VGPRs
// (loaded once); B-frag ds_read_b128 at row (lane&7), active iff lane's
// column half (lane>>3 & 1) == h (cndmask 0 -> exact integer accumulation).
// D layout: col(=output) = lane&15, row(=batch) = (lane>>4)*4 + reg.
__global__ void __launch_bounds__(256, 1)
k_gemm(const int* __restrict__ Wp, const float* __restrict__ wscale,
       const float* __restrict__ bias, const uint32_t* __restrict__ ws,
       float* __restrict__ out) {
  __shared__ uint32_t Wlds[2 * 8 * (PITCH_WB / 4)];  // 131,328 B
  __shared__ int red[4][32][4];
  __shared__ int s_sumx[BATCH];
  __shared__ float s_scale;

  const int t = threadIdx.x;
  const int wave = t >> 6, lane = t & 63;

  if (t < 64) {  // reduce 64 sum_x partials: index = b*8+seg
    int p = (int)ws[128 + t];
    p += __shfl_xor(p, 1);
    p += __shfl_xor(p, 2);
    p += __shfl_xor(p, 4);
    if ((t & 7) == 0) s_sumx[t >> 3] = p;
    if (t == 0) s_scale = (__uint_as_float(ws[0]) / 127.0f) * wscale[0];
  }
  __syncthreads();

  const uint8_t* W8 = (const uint8_t*)Wp;
  uint8_t* L8 = (uint8_t*)Wlds;

  // Stage (tile0, half0) into buffer 0.
  {
    const uint8_t* gs = W8 + (size_t)(blockIdx.x * 16 + 2 * wave) * 8192 + lane * 16;
    uint32_t* ld = (uint32_t*)(L8 + 2 * wave * PITCH_WB);
#pragma unroll
    for (int i = 0; i < 16; ++i)
      __builtin_amdgcn_global_load_lds(
          (const uint32_t*)(gs + i * 1024),
          ld + ((i >> 3) * PITCH_WB + (i & 7) * 1024) / 4, 16, 0, 0);
  }

  // A: this wave's K-quarter of transposed x_q -> 32 int4 in VGPRs.
  const uint8_t* xqT = (const uint8_t*)(ws + 1024);
  int4 a[32];
#pragma unroll
  for (int s = 0; s < 32; ++s)
    a[s] = *(const int4*)(xqT + (size_t)(wave * 32 + s) * 1024 + lane * 16);

  const int r8 = lane & 7, g = lane >> 4;
  const bool act0 = ((lane >> 3) & 1) == 0;  // column in rows 0..7 -> half 0

  const uint8_t* fr0 = L8 + r8 * PITCH_WB + wave * 2048 + g * 16;           // buf0
  const uint8_t* fr1 = L8 + HALF_B + r8 * PITCH_WB + wave * 2048 + g * 16;  // buf1

  for (int i = 0; i < 7; ++i) {
    i32x4 acc = {0, 0, 0, 0};

    // ---- phase A: compute (tile i, h=0) from buf0; stage (i, h=1) -> buf1
    {
      const uint8_t* gs =
          W8 + (size_t)((blockIdx.x + 256 * i) * 16 + 8 + 2 * wave) * 8192 + lane * 16;
      uint32_t* ld = (uint32_t*)(L8 + HALF_B + 2 * wave * PITCH_WB);
#pragma unroll
      for (int k = 0; k < 16; ++k)
        __builtin_amdgcn_global_load_lds(
            (const uint32_t*)(gs + k * 1024),
            ld + ((k >> 3) * PITCH_WB + (k & 7) * 1024) / 4, 16, 0, 0);
    }
    BAR_VM16;  // buf0's 16 DMAs (per wave) landed; buf1's 16 in flight
#pragma unroll
    for (int s = 0; s < 32; ++s) {
      int4 bw = *(const int4*)(fr0 + s * 64);
      i32x4 bf, af;
      bf.x = act0 ? unpack4((uint32_t)bw.x) : 0;
      bf.y = act0 ? unpack4((uint32_t)bw.y) : 0;
      bf.z = act0 ? unpack4((uint32_t)bw.z) : 0;
      bf.w = act0 ? unpack4((uint32_t)bw.w) : 0;
      af.x = a[s].x; af.y = a[s].y; af.z = a[s].z; af.w = a[s].w;
      acc = __builtin_amdgcn_mfma_i32_16x16x64_i8(af, bf, acc, 0, 0, 0);
    }
    BAR_LGKM;  // all waves done reading buf0 before it is restaged

    // ---- phase B: compute (tile i, h=1) from buf1; stage (i+1, h=0) -> buf0
    if (i < 6) {
      const uint8_t* gs =
          W8 + (size_t)((blockIdx.x + 256 * (i + 1)) * 16 + 2 * wave) * 8192 + lane * 16;
      uint32_t* ld = (uint32_t*)(L8 + 2 * wave * PITCH_WB);
#pragma unroll
      for (int k = 0; k < 16; ++k)
        __builtin_amdgcn_global_load_lds(
            (const uint32_t*)(gs + k * 1024),
            ld + ((k >> 3) * PITCH_WB + (k & 7) * 1024) / 4, 16, 0, 0);
      BAR_VM16;  // buf1 landed; next buf0 in flight
    } else {
      BAR_VM0;   // last phase: full drain
    }
#pragma unroll
    for (int s = 0; s < 32; ++s) {
      int4 bw = *(const int4*)(fr1 + s * 64);
      i32x4 bf, af;
      bf.x = act0 ? 0 : unpack4((uint32_t)bw.x);
      bf.y = act0 ? 0 : unpack4((uint32_t)bw.y);
      bf.z = act0 ? 0 : unpack4((uint32_t)bw.z);
      bf.w = act0 ? 0 : unpack4((uint32_t)bw.w);
      af.x = a[s].x; af.y = a[s].y; af.z = a[s].z; af.w = a[s].w;
      acc = __builtin_amdgcn_mfma_i32_16x16x64_i8(af, bf, acc, 0, 0, 0);
    }

    // ---- tile epilogue: cross-wave K-reduce + store (also protects buf1)
    if (lane < 32) {
#pragma unroll
      for (int r = 0; r < 4; ++r) red[wave][lane][r] = acc[r];
    }
    BAR_LGKM;  // red writes + buf1 ds_reads complete across all waves
    if (t < 32) {
      const int n = t & 15, q = t >> 4;
      const int o = (blockIdx.x + 256 * i) * 16 + n;
      const float bo = bias[o];
#pragma unroll
      for (int r = 0; r < 4; ++r) {
        int mm = q * 4 + r;  // batch row 0..7
        int tot = red[0][t][r] + red[1][t][r] + red[2][t][r] + red[3][t][r];
        out[mm * O_FEATS + o] = (float)(tot - s_sumx[mm]) * s_scale + bo;
      }
    }
    BAR_ONLY;  // red reads done before next tile's red writes
  }
}

extern "C" void kernel_launch(void* const* d_in, const int* in_sizes, int n_in,
                              void* d_out, int out_size, void* d_ws, size_t ws_size,
                              hipStream_t stream) {
  const float* x = (const float*)d_in[0];
  const int* pw = (const int*)d_in[1];
  const float* wscale = (const float*)d_in[2];
  const float* bias = (const float*)d_in[3];
  float* out = (float*)d_out;
  uint32_t* ws = (uint32_t*)d_ws;

  k_absmax<<<64, 256, 0, stream>>>(x, ws);
  k_quant<<<128, 256, 0, stream>>>(x, ws);
  k_gemm<<<256, 256, 0, stream>>>(pw, wscale, bias, ws, out);
}

// Round 11
// 338.011 us; speedup vs baseline: 1.0329x; 1.0329x over previous
//
#include <hip/hip_runtime.h>
#include <stdint.h>

#define O_FEATS 28672
#define I_FEATS 8192
#define BATCH 8
#define PITCH_CB 1040                // LDS bytes per row-chunk (1024 + 16 pad, 16B-aligned)
#define CHUNK_B (16 * PITCH_CB)     // one chunk buffer: 16,640 B

typedef int i32x4 __attribute__((ext_vector_type(4)));

// Pipelined barriers (asm + "memory" clobber: nothing moves across them).
// BAR_VM8: current chunk's 4 W-DMAs + 4 A-loads landed; next chunk's 8 stay
// in flight across the barrier (the non-draining AITER-style gate).
#define BAR_VM8  asm volatile("s_waitcnt vmcnt(8)\n\ts_barrier" ::: "memory")
#define BAR_VM0  asm volatile("s_waitcnt vmcnt(0)\n\ts_barrier" ::: "memory")
#define BAR_LGKM asm volatile("s_waitcnt lgkmcnt(0)\n\ts_barrier" ::: "memory")

// ---------------------------------------------------------------------------
// Workspace layout (uint32 word indices into ws):
//   ws[0]        : final absmax (float bits, >= 1e-5), written by k_quant
//   ws[16..79]   : per-block absmax partials (64 blocks of k_absmax)
//   ws[128..191] : per-block sum_x partials, index = b*8 + seg
//   ws[1024..]   : x_q TRANSPOSED to MFMA-fragment order, 128 KB:
//                  T[S*1024 + L*16 + j] = x_q[row L&15][k=S*64+(L>>4)*16+j]
//                  (S = global K-step 0..127, L = lane 0..63; rows 8..15 = 0)
// ---------------------------------------------------------------------------

// Carry-free unpack of 4 ternary codes (bits [7:0] of p) to 4 unsigned bytes
// {c0,c1,c2,c3} at byte positions 0..3 == k-offsets 0..3 of that word.
static __device__ __forceinline__ int unpack4(uint32_t p) {
  uint32_t lo = p & 0x0Fu;
  uint32_t hi = (p >> 4) & 0x0Fu;
  uint32_t a = (lo * 0x41u) & 0x0303u;
  uint32_t b = (hi * 0x41u) & 0x0303u;
  return (int)(a | (b << 16));
}

// 64 blocks x 256 threads x 4 floats = 65536 elements; per-block partial max.
__global__ void k_absmax(const float* __restrict__ x, uint32_t* __restrict__ ws) {
  __shared__ float red[4];
  int t = threadIdx.x;
  float4 v = ((const float4*)x)[blockIdx.x * 256 + t];
  float m = fmaxf(fmaxf(fabsf(v.x), fabsf(v.y)), fmaxf(fabsf(v.z), fabsf(v.w)));
#pragma unroll
  for (int off = 32; off; off >>= 1)
    m = fmaxf(m, __shfl_xor(m, off));
  if ((t & 63) == 0) red[t >> 6] = m;
  __syncthreads();
  if (t == 0)
    ws[16 + blockIdx.x] =
        __float_as_uint(fmaxf(fmaxf(red[0], red[1]), fmaxf(red[2], red[3])));
}

// 128 blocks. Blocks 0..63: (b = blk>>3, seg = blk&7) quantize 1024 elems of
// row b, write into transposed layout T + partial sums. Blocks 64..127:
// zero-fill pad rows 8..15 of T.
__global__ void k_quant(const float* __restrict__ x, uint32_t* __restrict__ ws) {
  __shared__ float s_amax;
  __shared__ int reds[4];
  int t = threadIdx.x;
  if (blockIdx.x >= 64) {  // zero pad rows 8..15 in T
    int row = 8 + ((blockIdx.x - 64) >> 3), seg = blockIdx.x & 7;
    int k0 = seg * 1024 + t * 4;
    int S = k0 >> 6, g = (k0 >> 4) & 3, j = k0 & 15;
    ws[1024 + ((S * 1024 + (g * 16 + row) * 16 + j) >> 2)] = 0u;
    return;
  }
  int b = blockIdx.x >> 3, seg = blockIdx.x & 7;
  if (t < 64) {  // reduce the 64 absmax partials (redundantly per block)
    float m = __uint_as_float(ws[16 + t]);
#pragma unroll
    for (int off = 32; off; off >>= 1)
      m = fmaxf(m, __shfl_xor(m, off));
    if (t == 0) {
      float a = fmaxf(m, 1e-5f);
      s_amax = a;
      ws[0] = __float_as_uint(a);  // same value from every block: benign
    }
  }
  __syncthreads();
  float s = s_amax / 127.0f;  // match ref: x / (absmax/127)
  float4 v = ((const float4*)(x + b * I_FEATS + seg * 1024))[t];
  int q0 = (int)fminf(fmaxf(rintf(v.x / s), -128.f), 127.f);
  int q1 = (int)fminf(fmaxf(rintf(v.y / s), -128.f), 127.f);
  int q2 = (int)fminf(fmaxf(rintf(v.z / s), -128.f), 127.f);
  int q3 = (int)fminf(fmaxf(rintf(v.w / s), -128.f), 127.f);
  uint32_t pk = (uint32_t)(q0 & 0xff) | ((uint32_t)(q1 & 0xff) << 8) |
                ((uint32_t)(q2 & 0xff) << 16) | ((uint32_t)(q3 & 0xff) << 24);
  {  // scatter into transposed fragment layout (4 B words, aligned)
    int k0 = seg * 1024 + t * 4;
    int S = k0 >> 6, g = (k0 >> 4) & 3, j = k0 & 15;
    ws[1024 + ((S * 1024 + (g * 16 + b) * 16 + j) >> 2)] = pk;
  }
  int s4 = q0 + q1 + q2 + q3;
#pragma unroll
  for (int off = 32; off; off >>= 1)
    s4 += __shfl_xor(s4, off);
  if ((t & 63) == 0) reds[t >> 6] = s4;
  __syncthreads();
  if (t == 0)
    ws[128 + blockIdx.x] = (uint32_t)(reds[0] + reds[1] + reds[2] + reds[3]);
}

// MFMA GEMM, non-draining double-buffered staging: 1792 blocks x 256 thr,
// 4 blocks/CU (LDS-bound at ~35 KB), 16 waves/CU. Block -> 16 output rows,
// K in 8 chunks of 1024 packed-bytes/row, chunk order XOR-permuted per
// block. Per chunk per wave: 4 W-DMAs (global_load_lds 1 KB: rows
// wave*4..+3) + 4 A-loads (next chunk's registers), then
// [vmcnt(8); barrier] -- current chunk landed, next chunk's 8 in flight.
// Compute: wave w owns k-window w*256+s*64 of the chunk; B-frag
// ds_read_b128 at row (lane&15), byte w*256+s*64+(lane>>4)*16;
// unpack4(word r) == frag reg r; A from registers (identical bytes to R8).
// [lgkmcnt(0); barrier] protects the buffer before restage (R9's bug).
// D layout: col(=output) = lane&15, row(=batch) = (lane>>4)*4 + reg.
__global__ void __launch_bounds__(256, 4)
k_gemm(const int* __restrict__ Wp, const float* __restrict__ wscale,
       const float* __restrict__ bias, const uint32_t* __restrict__ ws,
       float* __restrict__ out) {
  __shared__ uint8_t Wlds[2 * CHUNK_B];  // 33,280 B, two chunk buffers
  __shared__ int red[4][32][4];
  __shared__ int s_sumx[BATCH];
  __shared__ float s_scale;

  const int t = threadIdx.x;
  const int wave = t >> 6, lane = t & 63;

  if (t < 64) {  // reduce 64 sum_x partials: index = b*8+seg
    int p = (int)ws[128 + t];
    p += __shfl_xor(p, 1);
    p += __shfl_xor(p, 2);
    p += __shfl_xor(p, 4);
    if ((t & 7) == 0) s_sumx[t >> 3] = p;
    if (t == 0) s_scale = (__uint_as_float(ws[0]) / 127.0f) * wscale[0];
  }
  __syncthreads();  // drains preamble only (before any pipeline vmem)

  const int o_base = blockIdx.x * 16;
  const int m = lane & 15, g = lane >> 4;
  const int perm = blockIdx.x & 7;  // chunk-order XOR permutation

  const uint8_t* W8 = (const uint8_t*)Wp;
  const uint8_t* xqT = (const uint8_t*)(ws + 1024);

  // W staging source for this wave's 4 rows (chunk offset added per chunk)
  const uint8_t* gsrc = W8 + (size_t)(o_base + wave * 4) * 8192 + lane * 16;
  uint8_t* ldst = Wlds + (wave * 4) * PITCH_CB;
  // B fragment read base (within a chunk buffer)
  const uint8_t* fbase = Wlds + m * PITCH_CB + wave * 256 + g * 16;

#define STAGE_W(buf, cc)                                                      \
  {                                                                           \
    const uint8_t* gs = gsrc + (cc) * 1024;                                   \
    uint8_t* ld = ldst + (buf) * CHUNK_B;                                     \
    _Pragma("unroll") for (int i = 0; i < 4; ++i)                             \
        __builtin_amdgcn_global_load_lds((const uint32_t*)(gs + i * 8192),    \
                                         (uint32_t*)(ld + i * PITCH_CB), 16,  \
                                         0, 0);                               \
  }
#define LOAD_A(dst, cc)                                                       \
  {                                                                           \
    _Pragma("unroll") for (int s = 0; s < 4; ++s)(dst)[s] =                   \
        *(const int4*)(xqT + (size_t)(((cc) * 16 + wave * 4 + s) << 10) +     \
                       lane * 16);                                            \
  }

  i32x4 acc = {0, 0, 0, 0};
  int4 acur[4], anext[4];

  // Prologue: chunk cc(0) -> buf0, A(0) -> regs.
  STAGE_W(0, (0 ^ perm));
  LOAD_A(acur, (0 ^ perm));

#pragma unroll
  for (int c = 0; c < 8; ++c) {
    if (c < 7) {
      STAGE_W((c + 1) & 1, ((c + 1) ^ perm));  // 4 W-DMAs in flight
      LOAD_A(anext, ((c + 1) ^ perm));         // 4 A-loads in flight
      BAR_VM8;  // chunk c landed; chunk c+1's 8 ops stay in flight
    } else {
      BAR_VM0;  // last chunk: full drain
    }
    const uint8_t* fb = fbase + (c & 1) * CHUNK_B;
#pragma unroll
    for (int s = 0; s < 4; ++s) {
      int4 bw = *(const int4*)(fb + s * 64);
      i32x4 bf, af;
      bf.x = unpack4((uint32_t)bw.x);
      bf.y = unpack4((uint32_t)bw.y);
      bf.z = unpack4((uint32_t)bw.z);
      bf.w = unpack4((uint32_t)bw.w);
      af.x = acur[s].x; af.y = acur[s].y; af.z = acur[s].z; af.w = acur[s].w;
      acc = __builtin_amdgcn_mfma_i32_16x16x64_i8(af, bf, acc, 0, 0, 0);
    }
    BAR_LGKM;  // all waves done reading buf (c&1) before its restage
#pragma unroll
    for (int s = 0; s < 4; ++s) acur[s] = anext[s];
  }

  // Epilogue: cross-wave K-reduce + store.
  if (lane < 32) {  // batch rows 0..7 live in lanes 0..31
#pragma unroll
    for (int r = 0; r < 4; ++r) red[wave][lane][r] = acc[r];
  }
  __syncthreads();
  if (t < 32) {
    const int n = t & 15, q = t >> 4;
    const int o = o_base + n;
    const float bo = bias[o];
#pragma unroll
    for (int r = 0; r < 4; ++r) {
      int mm = q * 4 + r;  // batch row 0..7
      int tot = red[0][t][r] + red[1][t][r] + red[2][t][r] + red[3][t][r];
      out[mm * O_FEATS + o] = (float)(tot - s_sumx[mm]) * s_scale + bo;
    }
  }
#undef STAGE_W
#undef LOAD_A
}

extern "C" void kernel_launch(void* const* d_in, const int* in_sizes, int n_in,
                              void* d_out, int out_size, void* d_ws, size_t ws_size,
                              hipStream_t stream) {
  const float* x = (const float*)d_in[0];
  const int* pw = (const int*)d_in[1];
  const float* wscale = (const float*)d_in[2];
  const float* bias = (const float*)d_in[3];
  float* out = (float*)d_out;
  uint32_t* ws = (uint32_t*)d_ws;

  k_absmax<<<64, 256, 0, stream>>>(x, ws);
  k_quant<<<128, 256, 0, stream>>>(x, ws);
  k_gemm<<<O_FEATS / 16, 256, 0, stream>>>(pw, wscale, bias, ws, out);
}